// Round 3
// baseline (415.237 us; speedup 1.0000x reference)
//
#include <hip/hip_runtime.h>
#include <hip/hip_bf16.h>
#include <math.h>

#define BB 2
#define NN 2048
#define QD 1024
#define CTX_LEN 77
#define TCD 768
#define NUM_PROMPT 64
#define PD 1024
#define HEADS 8
#define DIM_HEAD 64
#define INNER 512
#define JTOT (CTX_LEN + NUM_PROMPT + NN)   // 2189
#define SCALE 0.125f
#define MTOT (BB * NN)                     // 4096
#define JPAD 2240                          // 35 * 64, padded j extent
#define NT_J (JPAD / 64)                   // 35 j-tiles

typedef unsigned short u16;
typedef unsigned int u32;
typedef __attribute__((ext_vector_type(8))) short bf16x8;
typedef __attribute__((ext_vector_type(4))) float f32x4;

__device__ __forceinline__ u32 pack_split(float f) {   // interleaved: low16=hi, high16=lo
  u32 u = __builtin_bit_cast(u32, f);
  u32 hi = u & 0xffff0000u;
  float lo = f - __builtin_bit_cast(float, hi);
  u32 ul = __builtin_bit_cast(u32, lo);
  return __builtin_amdgcn_perm(ul, u, 0x07060302u);
}
__device__ __forceinline__ void split2(float f, u16& h, u16& l) {
  u32 u = __builtin_bit_cast(u32, f);
  u32 hm = u & 0xffff0000u;
  float lo = f - __builtin_bit_cast(float, hm);
  h = (u16)(u >> 16);
  l = (u16)(__builtin_bit_cast(u32, lo) >> 16);
}

// DPP lane move within 16-lane rows (ctrl must be ICE -> template)
template <int CTRL>
__device__ __forceinline__ float dpp_f(float x) {
  int i = __builtin_bit_cast(int, x);
  i = __builtin_amdgcn_update_dpp(0, i, CTRL, 0xF, 0xF, false);
  return __builtin_bit_cast(float, i);
}

// async global->LDS, 16B per lane; lds dest = base + lane*16
__device__ __forceinline__ void gload16(const u16* g, u32* l) {
  __builtin_amdgcn_global_load_lds(
      (const __attribute__((address_space(1))) u32*)(const void*)g,
      (__attribute__((address_space(3))) u32*)(void*)l, 16, 0, 0);
}

// ---------------- merged f32 -> hi/lo plane pack (x and prompt in one launch) ----------------
__global__ __launch_bounds__(256) void pack_planes2(
    const float* __restrict__ s0, u16* __restrict__ d0h, u16* __restrict__ d0l, int n0,
    const float* __restrict__ s1, u16* __restrict__ d1h, u16* __restrict__ d1l, int n1) {
  int i = blockIdx.x * 256 + threadIdx.x;
  const float* s;
  u16 *dh, *dl;
  if (i < n0) { s = s0; dh = d0h; dl = d0l; }
  else {
    i -= n0;
    if (i >= n1) return;
    s = s1; dh = d1h; dl = d1l;
  }
  float4 f = ((const float4*)s)[i];
  ushort4 hh, ll;
  split2(f.x, hh.x, ll.x); split2(f.y, hh.y, ll.y);
  split2(f.z, hh.z, ll.z); split2(f.w, hh.w, ll.w);
  ((ushort4*)dh)[i] = hh;
  ((ushort4*)dl)[i] = ll;
}

// ---------------- merged weight transpose+pack: 6 sources, one launch ----------------
struct TP6 {
  const float* src[6];
  u16* dh[6];
  u16* dl[6];
  int K[6], N[6];
  int blk0[7];   // cumulative block offsets, blk0[6] = total blocks
};

__global__ __launch_bounds__(256) void transpose_pack6(TP6 P) {
  __shared__ u32 T[32][33];
  const int bid = blockIdx.x;
  int s = 0;
#pragma unroll
  for (int k = 1; k < 6; ++k) s += (bid >= P.blk0[k]);
  const int rel = bid - P.blk0[s];
  const int N = P.N[s], K = P.K[s];
  const int nbx = N >> 5;
  const int bx = rel % nbx, by = rel / nbx;
  const float* __restrict__ src = P.src[s];
  u16* __restrict__ dh = P.dh[s];
  u16* __restrict__ dl = P.dl[s];
  const int t = threadIdx.x;
  const int k0 = by * 32, n0 = bx * 32;
#pragma unroll
  for (int i = 0; i < 4; ++i) {
    int e = t + i * 256;
    int kr = e >> 5, nc = e & 31;
    T[kr][nc] = pack_split(src[(size_t)(k0 + kr) * N + n0 + nc]);
  }
  __syncthreads();
#pragma unroll
  for (int i = 0; i < 4; ++i) {
    int e = t + i * 256;
    int nr = e >> 5, kc = e & 31;
    u32 w = T[kc][nr];
    size_t idx = (size_t)(n0 + nr) * K + k0 + kc;
    dh[idx] = (u16)(w & 0xffff);
    dl[idx] = (u16)(w >> 16);
  }
}

// ---------------- split-bf16 MFMA GEMM, 128x64 tiles, BK=64 (two 32-col sub-buffers) ----------------
// MODE 0: plane output -> O1h/O1l [gm*Ntot+gn]
// MODE 1: gn<TCD -> ctx planes (row remap); else q planes (x SCALE) -> O2h/O2l
// MODE 2: gn<INNER -> K planes with JPAD row remap -> O1h/O1l; else V planes -> O2h/O2l
// MODE 3: f32 out + bias
template <int MODE>
__global__ __launch_bounds__(256) void gemm_mfma(
    const u16* __restrict__ Agh, const u16* __restrict__ Agl,
    const u16* __restrict__ Bgh, const u16* __restrict__ Bgl,
    u16* __restrict__ O1h, u16* __restrict__ O1l,
    u16* __restrict__ O2h, u16* __restrict__ O2l,
    float* __restrict__ Of, const float* __restrict__ bias,
    int M, int K, int Ntot) {
  __shared__ __align__(16) u32 Ah_s[2][128 * 16];
  __shared__ __align__(16) u32 Al_s[2][128 * 16];
  __shared__ __align__(16) u32 Bh_s[2][64 * 16];
  __shared__ __align__(16) u32 Bl_s[2][64 * 16];

  const int t = threadIdx.x;
  const int w = t >> 6, lane = t & 63;
  const int m16 = lane & 15, quad = lane >> 4;
  const int wm = w >> 1, wn = w & 1;
  const int bm = blockIdx.y * 128, bn = blockIdx.x * 64;

  // DMA staging geometry: 4 lanes per 64B row, lane's 16B slot = (lane&3)*8 u16.
  // Wave w: A rows 32w..32w+31 (2 calls of 16 rows), B rows 16w..16w+15 (1 call).
  const int acol = (lane & 3) * 8;
  const int ar0 = 32 * w + (lane >> 2);
  const int ar1 = ar0 + 16;
  const int ag0 = min(bm + ar0, M - 1);   // clamp: OOB rows read valid garbage,
  const int ag1 = min(bm + ar1, M - 1);   // results guarded out in epilogue
  const u16* a0h = Agh + (size_t)ag0 * K + acol;
  const u16* a1h = Agh + (size_t)ag1 * K + acol;
  const u16* a0l = Agl + (size_t)ag0 * K + acol;
  const u16* a1l = Agl + (size_t)ag1 * K + acol;
  const int br = 16 * w + (lane >> 2);
  const u16* b0h = Bgh + (size_t)(bn + br) * K + acol;
  const u16* b0l = Bgl + (size_t)(bn + br) * K + acol;

  f32x4 acc[4][2];
#pragma unroll
  for (int i = 0; i < 4; ++i)
#pragma unroll
    for (int j = 0; j < 2; ++j) acc[i][j] = (f32x4){0.f, 0.f, 0.f, 0.f};

  for (int k0 = 0; k0 < K; k0 += 64) {
    // ---- async stage both 32-col sub-tiles ----
#pragma unroll
    for (int s = 0; s < 2; ++s) {
      const int kc = k0 + s * 32;
      gload16(a0h + kc, &Ah_s[s][(2 * w) * 256]);
      gload16(a1h + kc, &Ah_s[s][(2 * w + 1) * 256]);
      gload16(a0l + kc, &Al_s[s][(2 * w) * 256]);
      gload16(a1l + kc, &Al_s[s][(2 * w + 1) * 256]);
      gload16(b0h + kc, &Bh_s[s][w * 256]);
      gload16(b0l + kc, &Bl_s[s][w * 256]);
    }
    __syncthreads();   // drains DMA (compiler emits vmcnt(0) before barrier)

#pragma unroll
    for (int s = 0; s < 2; ++s) {
      bf16x8 ah[4], al[4], bh[2], bl[2];
#pragma unroll
      for (int mt = 0; mt < 4; ++mt) {
        int off = (wm * 64 + mt * 16 + m16) * 16 + quad * 4;
        ah[mt] = *(const bf16x8*)&Ah_s[s][off];
        al[mt] = *(const bf16x8*)&Al_s[s][off];
      }
#pragma unroll
      for (int nt = 0; nt < 2; ++nt) {
        int off = (wn * 32 + nt * 16 + m16) * 16 + quad * 4;
        bh[nt] = *(const bf16x8*)&Bh_s[s][off];
        bl[nt] = *(const bf16x8*)&Bl_s[s][off];
      }
#pragma unroll
      for (int mt = 0; mt < 4; ++mt)
#pragma unroll
        for (int nt = 0; nt < 2; ++nt) {
          acc[mt][nt] = __builtin_amdgcn_mfma_f32_16x16x32_bf16(ah[mt], bh[nt], acc[mt][nt], 0, 0, 0);
          acc[mt][nt] = __builtin_amdgcn_mfma_f32_16x16x32_bf16(ah[mt], bl[nt], acc[mt][nt], 0, 0, 0);
          acc[mt][nt] = __builtin_amdgcn_mfma_f32_16x16x32_bf16(al[mt], bh[nt], acc[mt][nt], 0, 0, 0);
        }
    }
    __syncthreads();   // frag reads done before next DMA overwrites
  }

#pragma unroll
  for (int mt = 0; mt < 4; ++mt)
#pragma unroll
    for (int nt = 0; nt < 2; ++nt)
#pragma unroll
      for (int r = 0; r < 4; ++r) {
        int gm = bm + wm * 64 + mt * 16 + quad * 4 + r;
        int gn = bn + wn * 32 + nt * 16 + m16;
        float v = acc[mt][nt][r];
        u16 sh, sl;
        if (MODE == 0) {
          if (gm < M) {
            split2(v, sh, sl);
            size_t idx = (size_t)gm * Ntot + gn;
            O1h[idx] = sh; O1l[idx] = sl;
          }
        } else if (MODE == 1) {
          if (gn < TCD) {
            split2(v, sh, sl);
            size_t row = (size_t)(gm >> 11) * JTOT + 141 + (gm & 2047);
            O1h[row * TCD + gn] = sh; O1l[row * TCD + gn] = sl;
          } else {
            split2(v * SCALE, sh, sl);
            size_t idx = (size_t)gm * INNER + (gn - TCD);
            O2h[idx] = sh; O2l[idx] = sl;
          }
        } else if (MODE == 2) {
          if (gm < M) {
            split2(v, sh, sl);
            if (gn < INNER) {
              // K: remap to [B][JPAD][INNER]; pad rows hold garbage, masked in attn
              int row = (gm < JTOT) ? gm : (gm + (JPAD - JTOT));
              size_t idx = (size_t)row * INNER + gn;
              O1h[idx] = sh; O1l[idx] = sl;
            } else {
              size_t idx = (size_t)gm * INNER + (gn - INNER);
              O2h[idx] = sh; O2l[idx] = sl;
            }
          }
        } else {
          Of[(size_t)gm * QD + gn] = v + bias[gn];
        }
      }
}

__global__ __launch_bounds__(256) void copy_ctx_kernel(
    const float* __restrict__ context, const u16* __restrict__ pch,
    const u16* __restrict__ pcl, u16* __restrict__ ch, u16* __restrict__ cl) {
  int idx = blockIdx.x * 256 + threadIdx.x;
  const int total = BB * 141 * TCD;
  if (idx >= total) return;
  int c = idx % TCD;
  int r = (idx / TCD) % 141;
  int b = idx / (141 * TCD);
  size_t dst = ((size_t)b * JTOT + r) * TCD + c;
  if (r < CTX_LEN) {
    u16 sh, sl;
    split2(context[((size_t)b * CTX_LEN + r) * TCD + c], sh, sl);
    ch[dst] = sh; cl[dst] = sl;
  } else {
    size_t s = (size_t)(r - CTX_LEN) * TCD + c;
    ch[dst] = pch[s]; cl[dst] = pcl[s];
  }
}

// ---------------- V planes [MJ][INNER] -> V^T planes [B][INNER][JPAD], zero-padded ----------------
__global__ __launch_bounds__(256) void vtrans(
    const u16* __restrict__ vh, const u16* __restrict__ vl,
    u16* __restrict__ vth, u16* __restrict__ vtl) {
  __shared__ u16 T[64][65];
  const int j0 = blockIdx.x * 64;
  const int d0 = blockIdx.y * 64;
  const int bz = blockIdx.z;
  const int b = bz >> 1;
  const u16* src = (bz & 1) ? vl : vh;
  u16* dst = (bz & 1) ? vtl : vth;
  const int t = threadIdx.x;
#pragma unroll
  for (int i = 0; i < 16; ++i) {
    int e = i * 256 + t;
    int r = e >> 6, c = e & 63;           // r = j row, c = d col
    int jg = j0 + r;
    T[r][c] = (jg < JTOT) ? src[((size_t)b * JTOT + jg) * INNER + d0 + c] : (u16)0;
  }
  __syncthreads();
#pragma unroll
  for (int i = 0; i < 16; ++i) {
    int e = i * 256 + t;
    int r = e >> 6, c = e & 63;           // r = d row, c = j col
    dst[((size_t)b * INNER + d0 + r) * JPAD + j0 + c] = T[c][r];
  }
}

// ---------------- plane-format MFMA flash attention, T14 reg-staged prefetch ----------------
// K planes [B][JPAD][INNER], V^T planes [B][INNER][JPAD]; next tile loaded to regs
// during compute, published via ds_write_b128 at top of iteration (same LDS layout
// / source XOR-swizzle as before -> bitwise-identical data).
__global__ __launch_bounds__(256) void attn_mfma2(
    const u16* __restrict__ qhg, const u16* __restrict__ qlg,
    const u16* __restrict__ khg, const u16* __restrict__ klg,
    const u16* __restrict__ vtg_h, const u16* __restrict__ vtg_l,
    u16* __restrict__ aoh, u16* __restrict__ aol) {
  __shared__ __align__(16) u16 Kh_s[64 * 64];
  __shared__ __align__(16) u16 Kl_s[64 * 64];
  __shared__ __align__(16) u16 Vh_s[64 * 64];
  __shared__ __align__(16) u16 Vl_s[64 * 64];
  __shared__ __align__(16) u16 Ph_s[64 * 72];
  __shared__ __align__(16) u16 Pl_s[64 * 72];

  const int t = threadIdx.x;
  const int w = t >> 6, lane = t & 63;
  const int m16 = lane & 15, quad = lane >> 4;

  // XCD swizzle: 512 blocks = 8 * 64; each XCD gets 2 contiguous (b,h) groups
  const int id = blockIdx.x;
  const int swz = (id & 7) * 64 + (id >> 3);
  const int qt = swz & 31, bh = swz >> 5;
  const int b = bh >> 3, h = bh & 7;
  const int qrow0 = qt * 64;

  // Q fragments direct from global planes (A-frag: row=m16, k=ks*32+quad*8)
  bf16x8 qh[2], ql[2];
  {
    size_t qoff = ((size_t)(b * NN + qrow0 + w * 16 + m16)) * INNER + h * 64 + quad * 8;
#pragma unroll
    for (int ks = 0; ks < 2; ++ks) {
      qh[ks] = *(const bf16x8*)(qhg + qoff + ks * 32);
      ql[ks] = *(const bf16x8*)(qlg + qoff + ks * 32);
    }
  }

  // Staging: wave w owns plane w (0:Kh 1:Kl 2:Vh^T 3:Vl^T).
  // Per tile: 8 chunks of 1KB; LDS dest linear (chunk c, lane*16B), source chunk
  // slot = (lane&7)^(lane>>3) so LDS (row, cc) holds logical chunk cc^(row&7).
  const int sr = lane >> 3;
  const int sc = (lane & 7) ^ sr;
  const u16* gp;
  u32* lp;
  size_t cstr, jstr;
  if (w < 2) {
    gp = ((w == 0) ? khg : klg) + ((size_t)b * JPAD + sr) * INNER + h * 64 + sc * 8;
    lp = (u32*)((w == 0) ? Kh_s : Kl_s);
    cstr = (size_t)8 * INNER;
    jstr = (size_t)64 * INNER;
  } else {
    gp = ((w == 2) ? vtg_h : vtg_l) + ((size_t)b * INNER + h * 64 + sr) * JPAD + sc * 8;
    lp = (u32*)((w == 2) ? Vh_s : Vl_s);
    cstr = (size_t)8 * JPAD;
    jstr = 64;
  }

  f32x4 O[4] = {{0.f,0.f,0.f,0.f},{0.f,0.f,0.f,0.f},{0.f,0.f,0.f,0.f},{0.f,0.f,0.f,0.f}};
  float mrow[4], lrow[4];
#pragma unroll
  for (int r = 0; r < 4; ++r) { mrow[r] = -INFINITY; lrow[r] = 0.f; }

  // prologue: load tile 0 into regs
  uint4 st[8];
#pragma unroll
  for (int c = 0; c < 8; ++c) st[c] = *(const uint4*)(gp + (size_t)c * cstr);
  gp += jstr;

  for (int tile = 0; tile < NT_J; ++tile) {
    const int j0 = tile * 64;
    __syncthreads();                       // prior tile fully consumed
#pragma unroll
    for (int c = 0; c < 8; ++c)
      *(uint4*)(lp + c * 256 + lane * 4) = st[c];
    __syncthreads();                       // staged tile visible

    if (tile + 1 < NT_J) {                 // prefetch next tile (overlaps compute)
#pragma unroll
      for (int c = 0; c < 8; ++c) st[c] = *(const uint4*)(gp + (size_t)c * cstr);
      gp += jstr;
    }

    // ---- QK^T ----
    f32x4 S[4];
    __builtin_amdgcn_s_setprio(1);
#pragma unroll
    for (int jt = 0; jt < 4; ++jt) {
      const int row = jt * 16 + m16;
      f32x4 acc = {0.f, 0.f, 0.f, 0.f};
#pragma unroll
      for (int ks = 0; ks < 2; ++ks) {
        const int cc = row * 64 + (((ks * 4 + quad) ^ (row & 7)) << 3);
        bf16x8 kh = *(const bf16x8*)&Kh_s[cc];
        bf16x8 kl = *(const bf16x8*)&Kl_s[cc];
        acc = __builtin_amdgcn_mfma_f32_16x16x32_bf16(qh[ks], kh, acc, 0, 0, 0);
        acc = __builtin_amdgcn_mfma_f32_16x16x32_bf16(qh[ks], kl, acc, 0, 0, 0);
        acc = __builtin_amdgcn_mfma_f32_16x16x32_bf16(ql[ks], kh, acc, 0, 0, 0);
      }
      S[jt] = acc;
    }
    __builtin_amdgcn_s_setprio(0);

    // mask tail columns (also covers K pad-row garbage)
#pragma unroll
    for (int jt = 0; jt < 4; ++jt) {
      int jc = j0 + jt * 16 + m16;
      if (jc >= JTOT)
#pragma unroll
        for (int r = 0; r < 4; ++r) S[jt][r] = -INFINITY;
    }

    // ---- online softmax: DPP reductions over 16-lane rows (off the LDS pipe) ----
    float pj[4][4];
#pragma unroll
    for (int r = 0; r < 4; ++r) {
      float mx = fmaxf(fmaxf(S[0][r], S[1][r]), fmaxf(S[2][r], S[3][r]));
      mx = fmaxf(mx, dpp_f<0xB1>(mx));     // quad_perm [1,0,3,2] = xor1
      mx = fmaxf(mx, dpp_f<0x4E>(mx));     // quad_perm [2,3,0,1] = xor2
      mx = fmaxf(mx, dpp_f<0x124>(mx));    // row_ror:4
      mx = fmaxf(mx, dpp_f<0x128>(mx));    // row_ror:8
      float mnew = fmaxf(mrow[r], mx);
      float alpha = __expf(mrow[r] - mnew);
      mrow[r] = mnew;
      float rs = 0.f;
#pragma unroll
      for (int jt = 0; jt < 4; ++jt) {
        float pv = __expf(S[jt][r] - mnew);
        pj[jt][r] = pv;
        rs += pv;
      }
      rs += dpp_f<0xB1>(rs);
      rs += dpp_f<0x4E>(rs);
      rs += dpp_f<0x124>(rs);
      rs += dpp_f<0x128>(rs);
      lrow[r] = lrow[r] * alpha + rs;
#pragma unroll
      for (int nt = 0; nt < 4; ++nt) O[nt][r] *= alpha;
    }

    // ---- P -> LDS planes (rows are wave-private: no barrier needed) ----
#pragma unroll
    for (int jt = 0; jt < 4; ++jt)
#pragma unroll
      for (int r = 0; r < 4; ++r) {
        u16 sh, sl;
        split2(pj[jt][r], sh, sl);
        int pq = (w * 16 + quad * 4 + r) * 72 + jt * 16 + m16;
        Ph_s[pq] = sh;
        Pl_s[pq] = sl;
      }

    bf16x8 ph[2], pl[2];
#pragma unroll
    for (int ks = 0; ks < 2; ++ks) {
      int po = (w * 16 + m16) * 72 + ks * 32 + quad * 8;
      ph[ks] = *(const bf16x8*)&Ph_s[po];
      pl[ks] = *(const bf16x8*)&Pl_s[po];
    }

    // ---- PV (B-frag = V^T rows d) ----
    __builtin_amdgcn_s_setprio(1);
#pragma unroll
    for (int nt = 0; nt < 4; ++nt) {
      const int row = nt * 16 + m16;
#pragma unroll
      for (int ks = 0; ks < 2; ++ks) {
        const int cc = row * 64 + (((ks * 4 + quad) ^ (row & 7)) << 3);
        bf16x8 vh = *(const bf16x8*)&Vh_s[cc];
        bf16x8 vl = *(const bf16x8*)&Vl_s[cc];
        O[nt] = __builtin_amdgcn_mfma_f32_16x16x32_bf16(ph[ks], vh, O[nt], 0, 0, 0);
        O[nt] = __builtin_amdgcn_mfma_f32_16x16x32_bf16(ph[ks], vl, O[nt], 0, 0, 0);
        O[nt] = __builtin_amdgcn_mfma_f32_16x16x32_bf16(pl[ks], vh, O[nt], 0, 0, 0);
      }
    }
    __builtin_amdgcn_s_setprio(0);
  }

  float inv[4];
#pragma unroll
  for (int r = 0; r < 4; ++r) inv[r] = 1.f / lrow[r];
#pragma unroll
  for (int nt = 0; nt < 4; ++nt)
#pragma unroll
    for (int r = 0; r < 4; ++r) {
      size_t idx = ((size_t)(b * NN + qrow0 + w * 16 + quad * 4 + r)) * INNER +
                   h * 64 + nt * 16 + m16;
      u16 sh, sl;
      split2(O[nt][r] * inv[r], sh, sl);
      aoh[idx] = sh; aol[idx] = sl;
    }
}

// ---------------- launch ----------------
extern "C" void kernel_launch(void* const* d_in, const int* in_sizes, int n_in,
                              void* d_out, int out_size, void* d_ws, size_t ws_size,
                              hipStream_t stream) {
  const float* x        = (const float*)d_in[0];
  const float* context  = (const float*)d_in[1];
  const float* prompt   = (const float*)d_in[2];
  const float* w_prompt = (const float*)d_in[3];
  const float* w_img    = (const float*)d_in[4];
  const float* w_q      = (const float*)d_in[5];
  const float* w_k      = (const float*)d_in[6];
  const float* w_v      = (const float*)d_in[7];
  const float* w_out    = (const float*)d_in[8];
  const float* b_out    = (const float*)d_in[9];
  float* out = (float*)d_out;

  const int M = MTOT;             // 4096
  const int MJ = BB * JTOT;       // 4378

  u16* p = (u16*)d_ws;
  const size_t qN = (size_t)M * INNER;
  const size_t ctxN = (size_t)MJ * TCD;
  const size_t kN = (size_t)BB * JPAD * INNER;   // padded K planes
  const size_t vN = (size_t)MJ * INNER;
  u16* pch = p; p += (size_t)NUM_PROMPT * TCD;
  u16* pcl = p; p += (size_t)NUM_PROMPT * TCD;
  u16* cth = p; p += ctxN; u16* ctl = p; p += ctxN;
  u16* aoh = p; p += qN;   u16* aol = p; p += qN;
  u16* xh  = p; p += (size_t)M * QD;   u16* xl  = p; p += (size_t)M * QD;
  u16* prh = p; p += (size_t)NUM_PROMPT * PD;
  u16* prl = p; p += (size_t)NUM_PROMPT * PD;
  u16* WtPh = p; p += (size_t)TCD * PD;            u16* WtPl = p; p += (size_t)TCD * PD;
  u16* WtAh = p; p += (size_t)(TCD + INNER) * QD;  u16* WtAl = p; p += (size_t)(TCD + INNER) * QD;
  u16* WtBh = p; p += (size_t)(2 * INNER) * TCD;   u16* WtBl = p; p += (size_t)(2 * INNER) * TCD;
  u16* WtOh = p; p += (size_t)QD * INNER;          u16* WtOl = p; p += (size_t)QD * INNER;
  u16* qhp = p; p += qN;  u16* qlp = p; p += qN;   // q planes (pre-scaled)
  u16* khp = p; p += kN;  u16* klp = p; p += kN;   // K planes, JPAD rows per b
  u16* vhp = p; p += vN;  u16* vlp = p; p += vN;   // V planes
  u16* vthp = p; p += kN; u16* vtlp = p; p += kN;  // V^T planes [B][INNER][JPAD]

  // ---- pack inputs (one launch) ----
  const int n4x = M * QD / 4, n4p = NUM_PROMPT * PD / 4;
  pack_planes2<<<(n4x + n4p + 255) / 256, 256, 0, stream>>>(
      x, xh, xl, n4x, prompt, prh, prl, n4p);

  // ---- transpose+pack all 6 weights (one launch) ----
  TP6 tp;
  const float* srcs[6] = {w_prompt, w_img, w_q, w_k, w_v, w_out};
  u16* dhs[6] = {WtPh, WtAh, WtAh + (size_t)TCD * QD, WtBh, WtBh + (size_t)INNER * TCD, WtOh};
  u16* dls[6] = {WtPl, WtAl, WtAl + (size_t)TCD * QD, WtBl, WtBl + (size_t)INNER * TCD, WtOl};
  int Ks[6] = {PD, QD, QD, TCD, TCD, INNER};
  int Ns[6] = {TCD, TCD, INNER, INNER, INNER, QD};
  int acc_blk = 0;
  for (int i = 0; i < 6; ++i) {
    tp.src[i] = srcs[i]; tp.dh[i] = dhs[i]; tp.dl[i] = dls[i];
    tp.K[i] = Ks[i]; tp.N[i] = Ns[i];
    tp.blk0[i] = acc_blk;
    acc_blk += (Ns[i] / 32) * (Ks[i] / 32);
  }
  tp.blk0[6] = acc_blk;
  transpose_pack6<<<acc_blk, 256, 0, stream>>>(tp);

  // ---- prompt_ctx -> planes ----
  gemm_mfma<0><<<dim3(TCD / 64, 1), 256, 0, stream>>>(
      prh, prl, WtPh, WtPl, pch, pcl, nullptr, nullptr, nullptr, nullptr,
      NUM_PROMPT, PD, TCD);
  copy_ctx_kernel<<<(BB * 141 * TCD + 255) / 256, 256, 0, stream>>>(context, pch, pcl, cth, ctl);
  // ---- x @ [w_img | w_q] -> ctx planes (remap) + q planes (x SCALE) ----
  gemm_mfma<1><<<dim3((TCD + INNER) / 64, M / 128), 256, 0, stream>>>(
      xh, xl, WtAh, WtAl, cth, ctl, qhp, qlp, nullptr, nullptr,
      M, QD, TCD + INNER);
  // ---- ctx @ [w_k | w_v] -> K padded planes + V planes ----
  gemm_mfma<2><<<dim3((2 * INNER) / 64, (MJ + 127) / 128), 256, 0, stream>>>(
      cth, ctl, WtBh, WtBl, khp, klp, vhp, vlp, nullptr, nullptr,
      MJ, TCD, 2 * INNER);
  // ---- V -> V^T (zero-padded to JPAD) ----
  vtrans<<<dim3(NT_J, INNER / 64, BB * 2), 256, 0, stream>>>(vhp, vlp, vthp, vtlp);
  // ---- attention ----
  attn_mfma2<<<BB * HEADS * (NN / 64), 256, 0, stream>>>(
      qhp, qlp, khp, klp, vthp, vtlp, aoh, aol);
  // ---- out = ao @ w_out + b_out ----
  gemm_mfma<3><<<dim3(QD / 64, M / 128), 256, 0, stream>>>(
      aoh, aol, WtOh, WtOl, nullptr, nullptr, nullptr, nullptr, out, b_out,
      M, INNER, QD);
}

// Round 4
// 327.533 us; speedup vs baseline: 1.2678x; 1.2678x over previous
//
#include <hip/hip_runtime.h>
#include <hip/hip_bf16.h>
#include <math.h>

#define BB 2
#define NN 2048
#define QD 1024
#define CTX_LEN 77
#define TCD 768
#define NUM_PROMPT 64
#define PD 1024
#define HEADS 8
#define DIM_HEAD 64
#define INNER 512
#define JTOT (CTX_LEN + NUM_PROMPT + NN)   // 2189
#define SCALE 0.125f
#define MTOT (BB * NN)                     // 4096
#define JPAD 2240                          // 35 * 64, padded j extent
#define NT_J (JPAD / 64)                   // 35 j-tiles

typedef unsigned short u16;
typedef unsigned int u32;
typedef __attribute__((ext_vector_type(8))) short bf16x8;
typedef __attribute__((ext_vector_type(4))) float f32x4;

__device__ __forceinline__ u32 pack_split(float f) {   // interleaved: low16=hi, high16=lo
  u32 u = __builtin_bit_cast(u32, f);
  u32 hi = u & 0xffff0000u;
  float lo = f - __builtin_bit_cast(float, hi);
  u32 ul = __builtin_bit_cast(u32, lo);
  return __builtin_amdgcn_perm(ul, u, 0x07060302u);
}
__device__ __forceinline__ void split2(float f, u16& h, u16& l) {
  u32 u = __builtin_bit_cast(u32, f);
  u32 hm = u & 0xffff0000u;
  float lo = f - __builtin_bit_cast(float, hm);
  h = (u16)(u >> 16);
  l = (u16)(__builtin_bit_cast(u32, lo) >> 16);
}

// DPP lane move within 16-lane rows (ctrl must be ICE -> template)
template <int CTRL>
__device__ __forceinline__ float dpp_f(float x) {
  int i = __builtin_bit_cast(int, x);
  i = __builtin_amdgcn_update_dpp(0, i, CTRL, 0xF, 0xF, false);
  return __builtin_bit_cast(float, i);
}

// async global->LDS, 16B per lane; lds dest = base + lane*16
__device__ __forceinline__ void gload16(const u16* g, u32* l) {
  __builtin_amdgcn_global_load_lds(
      (const __attribute__((address_space(1))) u32*)(const void*)g,
      (__attribute__((address_space(3))) u32*)(void*)l, 16, 0, 0);
}

// ---------------- merged f32 -> hi/lo plane pack (x and prompt in one launch) ----------------
__global__ __launch_bounds__(256) void pack_planes2(
    const float* __restrict__ s0, u16* __restrict__ d0h, u16* __restrict__ d0l, int n0,
    const float* __restrict__ s1, u16* __restrict__ d1h, u16* __restrict__ d1l, int n1) {
  int i = blockIdx.x * 256 + threadIdx.x;
  const float* s;
  u16 *dh, *dl;
  if (i < n0) { s = s0; dh = d0h; dl = d0l; }
  else {
    i -= n0;
    if (i >= n1) return;
    s = s1; dh = d1h; dl = d1l;
  }
  float4 f = ((const float4*)s)[i];
  ushort4 hh, ll;
  split2(f.x, hh.x, ll.x); split2(f.y, hh.y, ll.y);
  split2(f.z, hh.z, ll.z); split2(f.w, hh.w, ll.w);
  ((ushort4*)dh)[i] = hh;
  ((ushort4*)dl)[i] = ll;
}

// ---------------- merged weight transpose+pack: 6 sources, one launch ----------------
struct TP6 {
  const float* src[6];
  u16* dh[6];
  u16* dl[6];
  int K[6], N[6];
  int blk0[7];   // cumulative block offsets, blk0[6] = total blocks
};

__global__ __launch_bounds__(256) void transpose_pack6(TP6 P) {
  __shared__ u32 T[32][33];
  const int bid = blockIdx.x;
  int s = 0;
#pragma unroll
  for (int k = 1; k < 6; ++k) s += (bid >= P.blk0[k]);
  const int rel = bid - P.blk0[s];
  const int N = P.N[s], K = P.K[s];
  const int nbx = N >> 5;
  const int bx = rel % nbx, by = rel / nbx;
  const float* __restrict__ src = P.src[s];
  u16* __restrict__ dh = P.dh[s];
  u16* __restrict__ dl = P.dl[s];
  const int t = threadIdx.x;
  const int k0 = by * 32, n0 = bx * 32;
#pragma unroll
  for (int i = 0; i < 4; ++i) {
    int e = t + i * 256;
    int kr = e >> 5, nc = e & 31;
    T[kr][nc] = pack_split(src[(size_t)(k0 + kr) * N + n0 + nc]);
  }
  __syncthreads();
#pragma unroll
  for (int i = 0; i < 4; ++i) {
    int e = t + i * 256;
    int nr = e >> 5, kc = e & 31;
    u32 w = T[kc][nr];
    size_t idx = (size_t)(n0 + nr) * K + k0 + kc;
    dh[idx] = (u16)(w & 0xffff);
    dl[idx] = (u16)(w >> 16);
  }
}

// ---------------- split-bf16 MFMA GEMM, 128x64 tiles, BK=64 (two 32-col sub-buffers) ----------------
// MODE 0: plane output -> O1h/O1l [gm*Ntot+gn]
// MODE 1: gn<TCD -> ctx planes (row remap); else q planes (x SCALE) -> O2h/O2l
// MODE 2: gn<INNER -> K planes with JPAD row remap -> O1h/O1l; else V planes -> O2h/O2l
// MODE 3: f32 out + bias
template <int MODE>
__global__ __launch_bounds__(256) void gemm_mfma(
    const u16* __restrict__ Agh, const u16* __restrict__ Agl,
    const u16* __restrict__ Bgh, const u16* __restrict__ Bgl,
    u16* __restrict__ O1h, u16* __restrict__ O1l,
    u16* __restrict__ O2h, u16* __restrict__ O2l,
    float* __restrict__ Of, const float* __restrict__ bias,
    int M, int K, int Ntot) {
  __shared__ __align__(16) u32 Ah_s[2][128 * 16];
  __shared__ __align__(16) u32 Al_s[2][128 * 16];
  __shared__ __align__(16) u32 Bh_s[2][64 * 16];
  __shared__ __align__(16) u32 Bl_s[2][64 * 16];

  const int t = threadIdx.x;
  const int w = t >> 6, lane = t & 63;
  const int m16 = lane & 15, quad = lane >> 4;
  const int wm = w >> 1, wn = w & 1;
  const int bm = blockIdx.y * 128, bn = blockIdx.x * 64;

  // DMA staging geometry: 4 lanes per 64B row, lane's 16B slot = (lane&3)*8 u16.
  // Wave w: A rows 32w..32w+31 (2 calls of 16 rows), B rows 16w..16w+15 (1 call).
  const int acol = (lane & 3) * 8;
  const int ar0 = 32 * w + (lane >> 2);
  const int ar1 = ar0 + 16;
  const int ag0 = min(bm + ar0, M - 1);   // clamp: OOB rows read valid garbage,
  const int ag1 = min(bm + ar1, M - 1);   // results guarded out in epilogue
  const u16* a0h = Agh + (size_t)ag0 * K + acol;
  const u16* a1h = Agh + (size_t)ag1 * K + acol;
  const u16* a0l = Agl + (size_t)ag0 * K + acol;
  const u16* a1l = Agl + (size_t)ag1 * K + acol;
  const int br = 16 * w + (lane >> 2);
  const u16* b0h = Bgh + (size_t)(bn + br) * K + acol;
  const u16* b0l = Bgl + (size_t)(bn + br) * K + acol;

  f32x4 acc[4][2];
#pragma unroll
  for (int i = 0; i < 4; ++i)
#pragma unroll
    for (int j = 0; j < 2; ++j) acc[i][j] = (f32x4){0.f, 0.f, 0.f, 0.f};

  for (int k0 = 0; k0 < K; k0 += 64) {
    // ---- async stage both 32-col sub-tiles ----
#pragma unroll
    for (int s = 0; s < 2; ++s) {
      const int kc = k0 + s * 32;
      gload16(a0h + kc, &Ah_s[s][(2 * w) * 256]);
      gload16(a1h + kc, &Ah_s[s][(2 * w + 1) * 256]);
      gload16(a0l + kc, &Al_s[s][(2 * w) * 256]);
      gload16(a1l + kc, &Al_s[s][(2 * w + 1) * 256]);
      gload16(b0h + kc, &Bh_s[s][w * 256]);
      gload16(b0l + kc, &Bl_s[s][w * 256]);
    }
    __syncthreads();   // drains DMA (compiler emits vmcnt(0) before barrier)

#pragma unroll
    for (int s = 0; s < 2; ++s) {
      bf16x8 ah[4], al[4], bh[2], bl[2];
#pragma unroll
      for (int mt = 0; mt < 4; ++mt) {
        int off = (wm * 64 + mt * 16 + m16) * 16 + quad * 4;
        ah[mt] = *(const bf16x8*)&Ah_s[s][off];
        al[mt] = *(const bf16x8*)&Al_s[s][off];
      }
#pragma unroll
      for (int nt = 0; nt < 2; ++nt) {
        int off = (wn * 32 + nt * 16 + m16) * 16 + quad * 4;
        bh[nt] = *(const bf16x8*)&Bh_s[s][off];
        bl[nt] = *(const bf16x8*)&Bl_s[s][off];
      }
#pragma unroll
      for (int mt = 0; mt < 4; ++mt)
#pragma unroll
        for (int nt = 0; nt < 2; ++nt) {
          acc[mt][nt] = __builtin_amdgcn_mfma_f32_16x16x32_bf16(ah[mt], bh[nt], acc[mt][nt], 0, 0, 0);
          acc[mt][nt] = __builtin_amdgcn_mfma_f32_16x16x32_bf16(ah[mt], bl[nt], acc[mt][nt], 0, 0, 0);
          acc[mt][nt] = __builtin_amdgcn_mfma_f32_16x16x32_bf16(al[mt], bh[nt], acc[mt][nt], 0, 0, 0);
        }
    }
    __syncthreads();   // frag reads done before next DMA overwrites
  }

#pragma unroll
  for (int mt = 0; mt < 4; ++mt)
#pragma unroll
    for (int nt = 0; nt < 2; ++nt)
#pragma unroll
      for (int r = 0; r < 4; ++r) {
        int gm = bm + wm * 64 + mt * 16 + quad * 4 + r;
        int gn = bn + wn * 32 + nt * 16 + m16;
        float v = acc[mt][nt][r];
        u16 sh, sl;
        if (MODE == 0) {
          if (gm < M) {
            split2(v, sh, sl);
            size_t idx = (size_t)gm * Ntot + gn;
            O1h[idx] = sh; O1l[idx] = sl;
          }
        } else if (MODE == 1) {
          if (gn < TCD) {
            split2(v, sh, sl);
            size_t row = (size_t)(gm >> 11) * JTOT + 141 + (gm & 2047);
            O1h[row * TCD + gn] = sh; O1l[row * TCD + gn] = sl;
          } else {
            split2(v * SCALE, sh, sl);
            size_t idx = (size_t)gm * INNER + (gn - TCD);
            O2h[idx] = sh; O2l[idx] = sl;
          }
        } else if (MODE == 2) {
          if (gm < M) {
            split2(v, sh, sl);
            if (gn < INNER) {
              // K: remap to [B][JPAD][INNER]; pad rows hold garbage, masked in attn
              int row = (gm < JTOT) ? gm : (gm + (JPAD - JTOT));
              size_t idx = (size_t)row * INNER + gn;
              O1h[idx] = sh; O1l[idx] = sl;
            } else {
              size_t idx = (size_t)gm * INNER + (gn - INNER);
              O2h[idx] = sh; O2l[idx] = sl;
            }
          }
        } else {
          Of[(size_t)gm * QD + gn] = v + bias[gn];
        }
      }
}

__global__ __launch_bounds__(256) void copy_ctx_kernel(
    const float* __restrict__ context, const u16* __restrict__ pch,
    const u16* __restrict__ pcl, u16* __restrict__ ch, u16* __restrict__ cl) {
  int idx = blockIdx.x * 256 + threadIdx.x;
  const int total = BB * 141 * TCD;
  if (idx >= total) return;
  int c = idx % TCD;
  int r = (idx / TCD) % 141;
  int b = idx / (141 * TCD);
  size_t dst = ((size_t)b * JTOT + r) * TCD + c;
  if (r < CTX_LEN) {
    u16 sh, sl;
    split2(context[((size_t)b * CTX_LEN + r) * TCD + c], sh, sl);
    ch[dst] = sh; cl[dst] = sl;
  } else {
    size_t s = (size_t)(r - CTX_LEN) * TCD + c;
    ch[dst] = pch[s]; cl[dst] = pcl[s];
  }
}

// ---------------- V planes [MJ][INNER] -> V^T planes [B][INNER][JPAD], zero-padded ----------------
__global__ __launch_bounds__(256) void vtrans(
    const u16* __restrict__ vh, const u16* __restrict__ vl,
    u16* __restrict__ vth, u16* __restrict__ vtl) {
  __shared__ u16 T[64][65];
  const int j0 = blockIdx.x * 64;
  const int d0 = blockIdx.y * 64;
  const int bz = blockIdx.z;
  const int b = bz >> 1;
  const u16* src = (bz & 1) ? vl : vh;
  u16* dst = (bz & 1) ? vtl : vth;
  const int t = threadIdx.x;
#pragma unroll
  for (int i = 0; i < 16; ++i) {
    int e = i * 256 + t;
    int r = e >> 6, c = e & 63;           // r = j row, c = d col
    int jg = j0 + r;
    T[r][c] = (jg < JTOT) ? src[((size_t)b * JTOT + jg) * INNER + d0 + c] : (u16)0;
  }
  __syncthreads();
#pragma unroll
  for (int i = 0; i < 16; ++i) {
    int e = i * 256 + t;
    int r = e >> 6, c = e & 63;           // r = d row, c = j col
    dst[((size_t)b * INNER + d0 + r) * JPAD + j0 + c] = T[c][r];
  }
}

// ---------------- plane-format MFMA flash attention (R1 measured-best structure) ----------------
// K planes [B][JPAD][INNER], V^T planes [B][INNER][JPAD]; staged via global_load_lds
// with pre-swizzled source (XOR chunk swizzle) -> conflict-free ds_read_b128 fragments.
__global__ __launch_bounds__(256) void attn_mfma2(
    const u16* __restrict__ qhg, const u16* __restrict__ qlg,
    const u16* __restrict__ khg, const u16* __restrict__ klg,
    const u16* __restrict__ vtg_h, const u16* __restrict__ vtg_l,
    u16* __restrict__ aoh, u16* __restrict__ aol) {
  __shared__ __align__(16) u16 Kh_s[64 * 64];
  __shared__ __align__(16) u16 Kl_s[64 * 64];
  __shared__ __align__(16) u16 Vh_s[64 * 64];
  __shared__ __align__(16) u16 Vl_s[64 * 64];
  __shared__ __align__(16) u16 Ph_s[64 * 72];
  __shared__ __align__(16) u16 Pl_s[64 * 72];

  const int t = threadIdx.x;
  const int w = t >> 6, lane = t & 63;
  const int m16 = lane & 15, quad = lane >> 4;

  // XCD swizzle: 512 blocks = 8 * 64; each XCD gets 2 contiguous (b,h) groups
  const int id = blockIdx.x;
  const int swz = (id & 7) * 64 + (id >> 3);
  const int qt = swz & 31, bh = swz >> 5;
  const int b = bh >> 3, h = bh & 7;
  const int qrow0 = qt * 64;

  // Q fragments direct from global planes (A-frag: row=m16, k=ks*32+quad*8)
  bf16x8 qh[2], ql[2];
  {
    size_t qoff = ((size_t)(b * NN + qrow0 + w * 16 + m16)) * INNER + h * 64 + quad * 8;
#pragma unroll
    for (int ks = 0; ks < 2; ++ks) {
      qh[ks] = *(const bf16x8*)(qhg + qoff + ks * 32);
      ql[ks] = *(const bf16x8*)(qlg + qoff + ks * 32);
    }
  }

  // Staging: wave w stages plane w (0:Kh 1:Kl 2:Vh^T 3:Vl^T).
  // Per call: 8 rows x 8 chunks of 16B; dest linear, source chunk = (lane&7)^(lane>>3)
  // so LDS (row, cc) holds logical chunk cc^(row&7).
  const int sr = lane >> 3;
  const int sc = (lane & 7) ^ sr;
  const u16* gp;
  u32* lp;
  size_t cstr, jstr;
  if (w < 2) {
    gp = ((w == 0) ? khg : klg) + ((size_t)b * JPAD + sr) * INNER + h * 64 + sc * 8;
    lp = (u32*)((w == 0) ? Kh_s : Kl_s);
    cstr = (size_t)8 * INNER;
    jstr = (size_t)64 * INNER;
  } else {
    gp = ((w == 2) ? vtg_h : vtg_l) + ((size_t)b * INNER + h * 64 + sr) * JPAD + sc * 8;
    lp = (u32*)((w == 2) ? Vh_s : Vl_s);
    cstr = (size_t)8 * JPAD;
    jstr = 64;
  }

  f32x4 O[4] = {{0.f,0.f,0.f,0.f},{0.f,0.f,0.f,0.f},{0.f,0.f,0.f,0.f},{0.f,0.f,0.f,0.f}};
  float mrow[4], lrow[4];
#pragma unroll
  for (int r = 0; r < 4; ++r) { mrow[r] = -INFINITY; lrow[r] = 0.f; }

  for (int tile = 0; tile < NT_J; ++tile) {
    const int j0 = tile * 64;
    __syncthreads();                       // prior tile fully consumed
#pragma unroll
    for (int c = 0; c < 8; ++c) gload16(gp + (size_t)c * cstr, lp + c * 256);
    gp += jstr;
    __syncthreads();                       // drain DMA (vmcnt(0) before barrier)

    // ---- QK^T ----
    f32x4 S[4];
    __builtin_amdgcn_s_setprio(1);
#pragma unroll
    for (int jt = 0; jt < 4; ++jt) {
      const int row = jt * 16 + m16;
      f32x4 acc = {0.f, 0.f, 0.f, 0.f};
#pragma unroll
      for (int ks = 0; ks < 2; ++ks) {
        const int cc = row * 64 + (((ks * 4 + quad) ^ (row & 7)) << 3);
        bf16x8 kh = *(const bf16x8*)&Kh_s[cc];
        bf16x8 kl = *(const bf16x8*)&Kl_s[cc];
        acc = __builtin_amdgcn_mfma_f32_16x16x32_bf16(qh[ks], kh, acc, 0, 0, 0);
        acc = __builtin_amdgcn_mfma_f32_16x16x32_bf16(qh[ks], kl, acc, 0, 0, 0);
        acc = __builtin_amdgcn_mfma_f32_16x16x32_bf16(ql[ks], kh, acc, 0, 0, 0);
      }
      S[jt] = acc;
    }
    __builtin_amdgcn_s_setprio(0);

    // mask tail columns (also covers K pad-row garbage)
#pragma unroll
    for (int jt = 0; jt < 4; ++jt) {
      int jc = j0 + jt * 16 + m16;
      if (jc >= JTOT)
#pragma unroll
        for (int r = 0; r < 4; ++r) S[jt][r] = -INFINITY;
    }

    // ---- online softmax: DPP reductions over 16-lane rows (off the LDS pipe) ----
    float pj[4][4];
#pragma unroll
    for (int r = 0; r < 4; ++r) {
      float mx = fmaxf(fmaxf(S[0][r], S[1][r]), fmaxf(S[2][r], S[3][r]));
      mx = fmaxf(mx, dpp_f<0xB1>(mx));     // quad_perm [1,0,3,2] = xor1
      mx = fmaxf(mx, dpp_f<0x4E>(mx));     // quad_perm [2,3,0,1] = xor2
      mx = fmaxf(mx, dpp_f<0x124>(mx));    // row_ror:4
      mx = fmaxf(mx, dpp_f<0x128>(mx));    // row_ror:8
      float mnew = fmaxf(mrow[r], mx);
      float alpha = __expf(mrow[r] - mnew);
      mrow[r] = mnew;
      float rs = 0.f;
#pragma unroll
      for (int jt = 0; jt < 4; ++jt) {
        float pv = __expf(S[jt][r] - mnew);
        pj[jt][r] = pv;
        rs += pv;
      }
      rs += dpp_f<0xB1>(rs);
      rs += dpp_f<0x4E>(rs);
      rs += dpp_f<0x124>(rs);
      rs += dpp_f<0x128>(rs);
      lrow[r] = lrow[r] * alpha + rs;
#pragma unroll
      for (int nt = 0; nt < 4; ++nt) O[nt][r] *= alpha;
    }

    // ---- P -> LDS planes (rows are wave-private: no barrier needed) ----
#pragma unroll
    for (int jt = 0; jt < 4; ++jt)
#pragma unroll
      for (int r = 0; r < 4; ++r) {
        u16 sh, sl;
        split2(pj[jt][r], sh, sl);
        int pq = (w * 16 + quad * 4 + r) * 72 + jt * 16 + m16;
        Ph_s[pq] = sh;
        Pl_s[pq] = sl;
      }

    bf16x8 ph[2], pl[2];
#pragma unroll
    for (int ks = 0; ks < 2; ++ks) {
      int po = (w * 16 + m16) * 72 + ks * 32 + quad * 8;
      ph[ks] = *(const bf16x8*)&Ph_s[po];
      pl[ks] = *(const bf16x8*)&Pl_s[po];
    }

    // ---- PV (B-frag = V^T rows d) ----
    __builtin_amdgcn_s_setprio(1);
#pragma unroll
    for (int nt = 0; nt < 4; ++nt) {
      const int row = nt * 16 + m16;
#pragma unroll
      for (int ks = 0; ks < 2; ++ks) {
        const int cc = row * 64 + (((ks * 4 + quad) ^ (row & 7)) << 3);
        bf16x8 vh = *(const bf16x8*)&Vh_s[cc];
        bf16x8 vl = *(const bf16x8*)&Vl_s[cc];
        O[nt] = __builtin_amdgcn_mfma_f32_16x16x32_bf16(ph[ks], vh, O[nt], 0, 0, 0);
        O[nt] = __builtin_amdgcn_mfma_f32_16x16x32_bf16(ph[ks], vl, O[nt], 0, 0, 0);
        O[nt] = __builtin_amdgcn_mfma_f32_16x16x32_bf16(pl[ks], vh, O[nt], 0, 0, 0);
      }
    }
    __builtin_amdgcn_s_setprio(0);
  }

  float inv[4];
#pragma unroll
  for (int r = 0; r < 4; ++r) inv[r] = 1.f / lrow[r];
#pragma unroll
  for (int nt = 0; nt < 4; ++nt)
#pragma unroll
    for (int r = 0; r < 4; ++r) {
      size_t idx = ((size_t)(b * NN + qrow0 + w * 16 + quad * 4 + r)) * INNER +
                   h * 64 + nt * 16 + m16;
      u16 sh, sl;
      split2(O[nt][r] * inv[r], sh, sl);
      aoh[idx] = sh; aol[idx] = sl;
    }
}

// ---------------- launch ----------------
extern "C" void kernel_launch(void* const* d_in, const int* in_sizes, int n_in,
                              void* d_out, int out_size, void* d_ws, size_t ws_size,
                              hipStream_t stream) {
  const float* x        = (const float*)d_in[0];
  const float* context  = (const float*)d_in[1];
  const float* prompt   = (const float*)d_in[2];
  const float* w_prompt = (const float*)d_in[3];
  const float* w_img    = (const float*)d_in[4];
  const float* w_q      = (const float*)d_in[5];
  const float* w_k      = (const float*)d_in[6];
  const float* w_v      = (const float*)d_in[7];
  const float* w_out    = (const float*)d_in[8];
  const float* b_out    = (const float*)d_in[9];
  float* out = (float*)d_out;

  const int M = MTOT;             // 4096
  const int MJ = BB * JTOT;       // 4378

  u16* p = (u16*)d_ws;
  const size_t qN = (size_t)M * INNER;
  const size_t ctxN = (size_t)MJ * TCD;
  const size_t kN = (size_t)BB * JPAD * INNER;   // padded K planes
  const size_t vN = (size_t)MJ * INNER;
  u16* pch = p; p += (size_t)NUM_PROMPT * TCD;
  u16* pcl = p; p += (size_t)NUM_PROMPT * TCD;
  u16* cth = p; p += ctxN; u16* ctl = p; p += ctxN;
  u16* aoh = p; p += qN;   u16* aol = p; p += qN;
  u16* xh  = p; p += (size_t)M * QD;   u16* xl  = p; p += (size_t)M * QD;
  u16* prh = p; p += (size_t)NUM_PROMPT * PD;
  u16* prl = p; p += (size_t)NUM_PROMPT * PD;
  u16* WtPh = p; p += (size_t)TCD * PD;            u16* WtPl = p; p += (size_t)TCD * PD;
  u16* WtAh = p; p += (size_t)(TCD + INNER) * QD;  u16* WtAl = p; p += (size_t)(TCD + INNER) * QD;
  u16* WtBh = p; p += (size_t)(2 * INNER) * TCD;   u16* WtBl = p; p += (size_t)(2 * INNER) * TCD;
  u16* WtOh = p; p += (size_t)QD * INNER;          u16* WtOl = p; p += (size_t)QD * INNER;
  u16* qhp = p; p += qN;  u16* qlp = p; p += qN;   // q planes (pre-scaled)
  u16* khp = p; p += kN;  u16* klp = p; p += kN;   // K planes, JPAD rows per b
  u16* vhp = p; p += vN;  u16* vlp = p; p += vN;   // V planes
  u16* vthp = p; p += kN; u16* vtlp = p; p += kN;  // V^T planes [B][INNER][JPAD]

  // ---- pack inputs (one launch) ----
  const int n4x = M * QD / 4, n4p = NUM_PROMPT * PD / 4;
  pack_planes2<<<(n4x + n4p + 255) / 256, 256, 0, stream>>>(
      x, xh, xl, n4x, prompt, prh, prl, n4p);

  // ---- transpose+pack all 6 weights (one launch) ----
  TP6 tp;
  const float* srcs[6] = {w_prompt, w_img, w_q, w_k, w_v, w_out};
  u16* dhs[6] = {WtPh, WtAh, WtAh + (size_t)TCD * QD, WtBh, WtBh + (size_t)INNER * TCD, WtOh};
  u16* dls[6] = {WtPl, WtAl, WtAl + (size_t)TCD * QD, WtBl, WtBl + (size_t)INNER * TCD, WtOl};
  int Ks[6] = {PD, QD, QD, TCD, TCD, INNER};
  int Ns[6] = {TCD, TCD, INNER, INNER, INNER, QD};
  int acc_blk = 0;
  for (int i = 0; i < 6; ++i) {
    tp.src[i] = srcs[i]; tp.dh[i] = dhs[i]; tp.dl[i] = dls[i];
    tp.K[i] = Ks[i]; tp.N[i] = Ns[i];
    tp.blk0[i] = acc_blk;
    acc_blk += (Ns[i] / 32) * (Ks[i] / 32);
  }
  tp.blk0[6] = acc_blk;
  transpose_pack6<<<acc_blk, 256, 0, stream>>>(tp);

  // ---- prompt_ctx -> planes ----
  gemm_mfma<0><<<dim3(TCD / 64, 1), 256, 0, stream>>>(
      prh, prl, WtPh, WtPl, pch, pcl, nullptr, nullptr, nullptr, nullptr,
      NUM_PROMPT, PD, TCD);
  copy_ctx_kernel<<<(BB * 141 * TCD + 255) / 256, 256, 0, stream>>>(context, pch, pcl, cth, ctl);
  // ---- x @ [w_img | w_q] -> ctx planes (remap) + q planes (x SCALE) ----
  gemm_mfma<1><<<dim3((TCD + INNER) / 64, M / 128), 256, 0, stream>>>(
      xh, xl, WtAh, WtAl, cth, ctl, qhp, qlp, nullptr, nullptr,
      M, QD, TCD + INNER);
  // ---- ctx @ [w_k | w_v] -> K padded planes + V planes ----
  gemm_mfma<2><<<dim3((2 * INNER) / 64, (MJ + 127) / 128), 256, 0, stream>>>(
      cth, ctl, WtBh, WtBl, khp, klp, vhp, vlp, nullptr, nullptr,
      MJ, TCD, 2 * INNER);
  // ---- V -> V^T (zero-padded to JPAD) ----
  vtrans<<<dim3(NT_J, INNER / 64, BB * 2), 256, 0, stream>>>(vhp, vlp, vthp, vtlp);
  // ---- attention ----
  attn_mfma2<<<BB * HEADS * (NN / 64), 256, 0, stream>>>(
      qhp, qlp, khp, klp, vthp, vtlp, aoh, aol);
  // ---- out = ao @ w_out + b_out ----
  gemm_mfma<3><<<dim3(QD / 64, M / 128), 256, 0, stream>>>(
      aoh, aol, WtOh, WtOl, nullptr, nullptr, nullptr, nullptr, out, b_out,
      M, INNER, QD);
}